// Round 1
// baseline (2088.517 us; speedup 1.0000x reference)
//
#include <hip/hip_runtime.h>
#include <cstddef>

#define HIDc 768
#define SLEN 2048
#define BB 4
#define NH 6
#define DH 64
#define AHSc 384
#define KW 9
#define BS_TOT 8192
#define HALFc 384

// ---------------- generic tiled fp32 GEMM: C[M,N] = A[M,Kd]@B[Kd,N] + bias ----------------
// A row-major (lda), B row-major (ldb), C row-major (ldc) with column offset coff.
// Tiles: 64x64, BK=16, 256 threads, 4x4 micro-tile per thread.
__global__ __launch_bounds__(256)
void gemm64(const float* __restrict__ A, const float* __restrict__ Bm,
            const float* __restrict__ bias, float* __restrict__ C,
            int Kd, int lda, int ldb, int ldc, int coff)
{
    __shared__ float As[16][65];   // padded: conflict-free transposed store
    __shared__ float Bs[16][64];
    const int tid = threadIdx.x;
    const int tx = tid & 15, ty = tid >> 4;
    const int row0 = blockIdx.y * 64;
    const int col0 = blockIdx.x * 64;
    float acc[4][4] = {};
    for (int kt = 0; kt < Kd; kt += 16) {
#pragma unroll
        for (int i = 0; i < 4; ++i) {
            int idx = tid + i * 256;
            int r = idx >> 4, c = idx & 15;
            As[c][r] = A[(size_t)(row0 + r) * lda + kt + c];
        }
#pragma unroll
        for (int i = 0; i < 4; ++i) {
            int idx = tid + i * 256;
            int r = idx >> 6, c = idx & 63;
            Bs[r][c] = Bm[(size_t)(kt + r) * ldb + col0 + c];
        }
        __syncthreads();
#pragma unroll
        for (int kk = 0; kk < 16; ++kk) {
            float a[4], b[4];
#pragma unroll
            for (int i = 0; i < 4; ++i) a[i] = As[kk][ty * 4 + i];
#pragma unroll
            for (int j = 0; j < 4; ++j) b[j] = Bs[kk][tx * 4 + j];
#pragma unroll
            for (int i = 0; i < 4; ++i)
#pragma unroll
                for (int j = 0; j < 4; ++j) acc[i][j] += a[i] * b[j];
        }
        __syncthreads();
    }
#pragma unroll
    for (int i = 0; i < 4; ++i) {
        int r = row0 + ty * 4 + i;
#pragma unroll
        for (int j = 0; j < 4; ++j) {
            int c = col0 + tx * 4 + j;
            C[(size_t)r * ldc + coff + c] = acc[i][j] + bias[c];
        }
    }
}

// ---------------- depthwise conv over sequence, output [B,S,HID] ----------------
__global__ __launch_bounds__(256)
void dwconv_kernel(const float* __restrict__ x, const float* __restrict__ kern,
                   float* __restrict__ dwT)
{
    int idx = blockIdx.x * 256 + threadIdx.x;   // over BS_TOT*HID
    int c = idx % HIDc;
    int bs = idx / HIDc;
    int b = bs / SLEN, s = bs % SLEN;
    float acc = 0.f;
#pragma unroll
    for (int t = 0; t < KW; ++t) {
        int ss = s + t - KW / 2;
        if (ss >= 0 && ss < SLEN)
            acc += x[(size_t)(b * SLEN + ss) * HIDc + c] * kern[c * KW + t];
    }
    dwT[idx] = acc;
}

// ---------------- transpose pw_kernel [AHS,HID] -> [HID,AHS] ----------------
__global__ __launch_bounds__(256)
void transpose_pw(const float* __restrict__ pw, float* __restrict__ pwT)
{
    int idx = blockIdx.x * 256 + threadIdx.x;   // over AHS*HID
    int o = idx / HIDc, c = idx % HIDc;
    pwT[c * AHSc + o] = pw[idx];
}

// ---------------- fused conv-attention path ----------------
// per (b,s): conv_attn = ks_out*q; filt = conv_attn@Wak+bak; softmax over 9 taps;
// conv_out[h*64+d] = sum_k v[s+k-4, h*64+d] * filt[h,k]
__global__ __launch_bounds__(384)
void convattn_kernel(const float* __restrict__ ksout, const float* __restrict__ q,
                     const float* __restrict__ v, const float* __restrict__ Wak,
                     const float* __restrict__ bak, float* __restrict__ conv_out)
{
    __shared__ float ca[AHSc];
    __shared__ float part[7][54];
    __shared__ float filt[54];
    int bs = blockIdx.x;
    int b = bs / SLEN, s = bs % SLEN;
    int t = threadIdx.x;
    ca[t] = ksout[(size_t)bs * AHSc + t] * q[(size_t)bs * AHSc + t];
    __syncthreads();
    if (t < 378) {
        int o = t % 54, g = t / 54;
        int c0 = g * 55, c1 = c0 + 55 > AHSc ? AHSc : c0 + 55;
        float acc = 0.f;
        for (int c = c0; c < c1; ++c) acc += ca[c] * Wak[c * 54 + o];
        part[g][o] = acc;
    }
    __syncthreads();
    if (t < 54) {
        float acc = bak[t];
#pragma unroll
        for (int g = 0; g < 7; ++g) acc += part[g][t];
        filt[t] = acc;
    }
    __syncthreads();
    if (t < NH) {
        float m = -1e30f;
#pragma unroll
        for (int k = 0; k < KW; ++k) m = fmaxf(m, filt[t * KW + k]);
        float sum = 0.f; float e[KW];
#pragma unroll
        for (int k = 0; k < KW; ++k) { e[k] = __expf(filt[t * KW + k] - m); sum += e[k]; }
        float inv = 1.f / sum;
#pragma unroll
        for (int k = 0; k < KW; ++k) filt[t * KW + k] = e[k] * inv;
    }
    __syncthreads();
    int h = t >> 6;
    float acc = 0.f;
#pragma unroll
    for (int k = 0; k < KW; ++k) {
        int ss = s + k - KW / 2;
        if (ss >= 0 && ss < SLEN)
            acc += v[(size_t)(b * SLEN + ss) * AHSc + t] * filt[h * KW + k];
    }
    conv_out[(size_t)bs * AHSc + t] = acc;
}

// ---------------- attention scores: per (b,h) [2048,64]@[64,2048]/8 + mask ----------------
__global__ __launch_bounds__(256)
void scores_kernel(const float* __restrict__ q, const float* __restrict__ k,
                   const float* __restrict__ mask, float* __restrict__ scores)
{
    __shared__ float Qs[64][68];
    __shared__ float Ks[64][68];
    int bh = blockIdx.z; int b = bh / NH, h = bh % NH;
    int q0 = blockIdx.y * 64, k0 = blockIdx.x * 64;
    int tid = threadIdx.x;
#pragma unroll
    for (int i = 0; i < 16; ++i) {
        int idx = tid + i * 256;
        int r = idx >> 6, c = idx & 63;
        Qs[r][c] = q[(size_t)(b * SLEN + q0 + r) * AHSc + h * 64 + c];
        Ks[r][c] = k[(size_t)(b * SLEN + k0 + r) * AHSc + h * 64 + c];
    }
    __syncthreads();
    int tx = tid & 15, ty = tid >> 4;
    float acc[4][4] = {};
#pragma unroll
    for (int d = 0; d < DH; ++d) {
        float a[4], bb[4];
#pragma unroll
        for (int i = 0; i < 4; ++i) a[i] = Qs[ty * 4 + i][d];
#pragma unroll
        for (int j = 0; j < 4; ++j) bb[j] = Ks[tx * 4 + j][d];
#pragma unroll
        for (int i = 0; i < 4; ++i)
#pragma unroll
            for (int j = 0; j < 4; ++j) acc[i][j] += a[i] * bb[j];
    }
#pragma unroll
    for (int i = 0; i < 4; ++i) {
        int qq = q0 + ty * 4 + i;
#pragma unroll
        for (int j = 0; j < 4; ++j) {
            int kk2 = k0 + tx * 4 + j;
            scores[((size_t)bh * SLEN + qq) * SLEN + kk2] =
                acc[i][j] * 0.125f + mask[b * SLEN + kk2];
        }
    }
}

// ---------------- row softmax stats: m and 1/l per score row ----------------
__global__ __launch_bounds__(256)
void rowstats_kernel(const float* __restrict__ scores, float* __restrict__ stats)
{
    __shared__ float red[256];
    int row = blockIdx.x;               // bh*2048 + qpos
    const float* sc = scores + (size_t)row * SLEN;
    int t = threadIdx.x;
    float vals[8]; float lm = -1e30f;
#pragma unroll
    for (int i = 0; i < 8; ++i) { vals[i] = sc[t + i * 256]; lm = fmaxf(lm, vals[i]); }
    red[t] = lm; __syncthreads();
    for (int s2 = 128; s2 > 0; s2 >>= 1) {
        if (t < s2) red[t] = fmaxf(red[t], red[t + s2]);
        __syncthreads();
    }
    float m = red[0]; __syncthreads();
    float ls = 0.f;
#pragma unroll
    for (int i = 0; i < 8; ++i) ls += __expf(vals[i] - m);
    red[t] = ls; __syncthreads();
    for (int s2 = 128; s2 > 0; s2 >>= 1) {
        if (t < s2) red[t] += red[t + s2];
        __syncthreads();
    }
    if (t == 0) { stats[row * 2] = m; stats[row * 2 + 1] = 1.f / red[0]; }
}

// ---------------- PV: attn_out[64-row tile] = softmax(scores)@V ----------------
__global__ __launch_bounds__(256)
void pv_kernel(const float* __restrict__ scores, const float* __restrict__ stats,
               const float* __restrict__ v, float* __restrict__ attn_out)
{
    __shared__ float Ps[64][65];   // [k][row], transposed with pad
    __shared__ float Vs[64][65];   // [k][d]
    int bh = blockIdx.z; int b = bh / NH, h = bh % NH;
    int q0 = blockIdx.y * 64;
    int tid = threadIdx.x;
    int tx = tid & 15, ty = tid >> 4;
    float acc[4][4] = {};
    const float* srow = scores + ((size_t)bh * SLEN + q0) * SLEN;
    for (int kt = 0; kt < SLEN; kt += 64) {
#pragma unroll
        for (int i = 0; i < 16; ++i) {
            int idx = tid + i * 256;
            int r = idx >> 6, c = idx & 63;
            float mval = stats[(bh * SLEN + q0 + r) * 2 + 0];
            float linv = stats[(bh * SLEN + q0 + r) * 2 + 1];
            Ps[c][r] = __expf(srow[(size_t)r * SLEN + kt + c] - mval) * linv;
            Vs[r][c] = v[(size_t)(b * SLEN + kt + r) * AHSc + h * 64 + c];
        }
        __syncthreads();
#pragma unroll
        for (int kk = 0; kk < 64; ++kk) {
            float a[4], bb[4];
#pragma unroll
            for (int i = 0; i < 4; ++i) a[i] = Ps[kk][ty * 4 + i];
#pragma unroll
            for (int j = 0; j < 4; ++j) bb[j] = Vs[kk][tx * 4 + j];
#pragma unroll
            for (int i = 0; i < 4; ++i)
#pragma unroll
                for (int j = 0; j < 4; ++j) acc[i][j] += a[i] * bb[j];
        }
        __syncthreads();
    }
#pragma unroll
    for (int i = 0; i < 4; ++i)
#pragma unroll
        for (int j = 0; j < 4; ++j)
            attn_out[(size_t)(b * SLEN + q0 + ty * 4 + i) * AHSc + h * 64 + tx * 4 + j] = acc[i][j];
}

extern "C" void kernel_launch(void* const* d_in, const int* in_sizes, int n_in,
                              void* d_out, int out_size, void* d_ws, size_t ws_size,
                              hipStream_t stream)
{
    const float* hidden = (const float*)d_in[0];
    const float* mask   = (const float*)d_in[1];
    const float* Wq  = (const float*)d_in[2];
    const float* bq  = (const float*)d_in[3];
    const float* Wk  = (const float*)d_in[4];
    const float* bk  = (const float*)d_in[5];
    const float* Wv  = (const float*)d_in[6];
    const float* bv  = (const float*)d_in[7];
    const float* dwk = (const float*)d_in[8];
    const float* pw  = (const float*)d_in[9];
    const float* sepb= (const float*)d_in[10];
    const float* Wak = (const float*)d_in[11];
    const float* bak = (const float*)d_in[12];
    const float* Wsl = (const float*)d_in[13];
    const float* bsl = (const float*)d_in[14];
    const float* Wcl = (const float*)d_in[15];
    const float* bcl = (const float*)d_in[16];

    float* out = (float*)d_out;
    float* ctx_out  = out;                     // [8192,768]
    float* attn_out = out + 6291456;           // [8192,384]
    float* scores   = out + 9437184;           // [24,2048,2048]

    float* ws = (float*)d_ws;
    float* q        = ws;                      // 3145728
    float* kbuf     = ws + 3145728;            // 3145728
    float* vbuf     = ws + 6291456;            // 3145728
    float* dwT      = ws + 9437184;            // 6291456 (dead after pointwise GEMM)
    float* conv_out = ws + 9437184;            // 3145728 (reuses dwT region)
    float* stats    = ws + 12582912;           // 98304
    float* ksout    = ws + 15728640;           // 3145728
    float* pwT      = ws + 18874368;           // 294912
    (void)in_sizes; (void)n_in; (void)out_size; (void)ws_size;

    dim3 blk(256);
    dim3 gemm_grid(AHSc / 64, BS_TOT / 64);    // (6,128)

    // QKV projections
    gemm64<<<gemm_grid, blk, 0, stream>>>(hidden, Wq, bq, q,    HIDc, HIDc, AHSc, AHSc, 0);
    gemm64<<<gemm_grid, blk, 0, stream>>>(hidden, Wk, bk, kbuf, HIDc, HIDc, AHSc, AHSc, 0);
    gemm64<<<gemm_grid, blk, 0, stream>>>(hidden, Wv, bv, vbuf, HIDc, HIDc, AHSc, AHSc, 0);

    // separable conv: depthwise then pointwise
    dwconv_kernel<<<BS_TOT * HIDc / 256, blk, 0, stream>>>(hidden, dwk, dwT);
    transpose_pw<<<AHSc * HIDc / 256, blk, 0, stream>>>(pw, pwT);
    gemm64<<<gemm_grid, blk, 0, stream>>>(dwT, pwT, sepb, ksout, HIDc, HIDc, AHSc, AHSc, 0);

    // conv-attention path -> conv_out
    convattn_kernel<<<dim3(BS_TOT), dim3(384), 0, stream>>>(ksout, q, vbuf, Wak, bak, conv_out);

    // self-attention: scores (output), softmax stats, PV
    scores_kernel<<<dim3(SLEN / 64, SLEN / 64, BB * NH), blk, 0, stream>>>(q, kbuf, mask, scores);
    rowstats_kernel<<<dim3(BB * NH * SLEN), blk, 0, stream>>>(scores, stats);
    pv_kernel<<<dim3(1, SLEN / 64, BB * NH), blk, 0, stream>>>(scores, stats, vbuf, attn_out);

    // final mix: ctx = [attn_out@Wsl+bsl , conv_out@Wcl+bcl]
    gemm64<<<gemm_grid, blk, 0, stream>>>(attn_out, Wsl, bsl, ctx_out, AHSc, AHSc, HALFc, HIDc, 0);
    gemm64<<<gemm_grid, blk, 0, stream>>>(conv_out, Wcl, bcl, ctx_out, AHSc, AHSc, HALFc, HIDc, HALFc);
}